// Round 16
// baseline (24.412 us; speedup 1.0000x reference)
//
#include <hip/hip_runtime.h>

typedef __attribute__((ext_vector_type(8)))  short short8;
typedef __attribute__((ext_vector_type(16))) float f32x16;
typedef __attribute__((ext_vector_type(16))) unsigned u32x16;

#define NPTS 2048
#define BATCH 32
#define NUM_CLASSES 6
#define THREADS 256
#define CC 2                 // candidate chunks per (dir,batch)
#define CANDS_BLK 1024       // NPTS / CC
#define CTILES 32            // CANDS_BLK / 32
#define QC 8                 // query chunks of 256
#define GROUPS 512           // 2 * 32 * 8
// grid1 = GROUPS * CC = 1024
#define BF16_ONE ((short)0x3F80)
#define FMAX_BITS 0x7F7FFFFFu
// ws: pmin[GROUPS][CC][256] floats (256K), then partial[GROUPS]
#define PART_OFF (GROUPS * CC * 256)

__device__ __forceinline__ unsigned short f2bf(float x) {
    union { float f; unsigned u; } v; v.f = x;
    unsigned r = v.u + 0x7FFF + ((v.u >> 16) & 1);   // RNE to bf16
    return (unsigned short)(r >> 16);
}
__device__ __forceinline__ float bf2f(unsigned short h) {
    union { unsigned u; float f; } v; v.u = ((unsigned)h) << 16; return v.f;
}
__device__ __forceinline__ unsigned f2u(float x) {
    union { float f; unsigned u; } v; v.f = x; return v.u;
}
__device__ __forceinline__ float u2f(unsigned x) {
    union { unsigned u; float f; } v; v.u = x; return v.f;
}
// Distances strictly positive -> uint compare == float compare; umin chains
// match v_min3_u32, no canonicalize, no inline asm (R14/R15 lessons).
__device__ __forceinline__ unsigned umin2(unsigned a, unsigned b) {
    return a < b ? a : b;
}

// K-slot plan (K=16), D = a2 + b2 - 2 a.b (absmax-0 verified R3-R15):
//  k0-2: A=ah B=-2bh | k3-5: A=al B=-2bh | k6-8: A=ah B=-2bl
//  k9: A=1 B=b2h | k10: A=1 B=b2l | k11: A=a2h B=1 | k12: A=a2l B=1 | k13-15: 0
// LDS: per 32-cand tile, 1024 B = [32 x kg0][32 x kg1]; wave reads contiguous
// 1 KB (R13-verified conflict-free).
// __launch_bounds__(256,4): 128-VGPR budget -> 4 waves/SIMD (16 waves/CU with
// 32 KB LDS). Peak live ~110 regs (pairwise fold) should fit without the
// AGPR-copy mode R13 hit at budget 88.
__global__ __launch_bounds__(THREADS, 4) void chamfer_pass1(
    const float* __restrict__ inst, const float* __restrict__ model,
    float* __restrict__ pmin)
{
    __shared__ char cands[CANDS_BLK * 32];   // 32 KB

    const int blk   = blockIdx.x;
    const int cc    = blk & 1;
    const int qc    = (blk >> 1) & 7;
    const int batch = (blk >> 4) & 31;
    const int dir   = blk >> 9;
    const int g     = (dir * BATCH + batch) * QC + qc;
    const int tid   = threadIdx.x;
    const int lane  = tid & 63, wid = tid >> 6;
    const int lh    = lane >> 5, lr = lane & 31;

    const float* __restrict__ Q  = dir ? model : inst;
    const float* __restrict__ Cp = dir ? inst  : model;

    // ---- stage 1024 candidates into tiled B-frag layout (4 per thread) ----
    const float* cb = Cp + ((size_t)batch * NPTS + (size_t)cc * CANDS_BLK) * 3;
    #pragma unroll
    for (int k = 0; k < CANDS_BLK / THREADS; ++k) {
        const int c = tid + k * THREADS;
        float bx = cb[c*3+0], by = cb[c*3+1], bz = cb[c*3+2];
        float m2x = -2.f*bx, m2y = -2.f*by, m2z = -2.f*bz;
        unsigned short hx = f2bf(m2x), hy = f2bf(m2y), hz = f2bf(m2z);
        unsigned short lx = f2bf(m2x - bf2f(hx));
        unsigned short ly = f2bf(m2y - bf2f(hy));
        unsigned short lz = f2bf(m2z - bf2f(hz));
        float b2 = fmaf(bx,bx, fmaf(by,by, bz*bz));
        unsigned short b2h = f2bf(b2);
        unsigned short b2l = f2bf(b2 - bf2f(b2h));
        short8 kg0 = { (short)hx,(short)hy,(short)hz,(short)hx,(short)hy,(short)hz,(short)lx,(short)ly };
        short8 kg1 = { (short)lz,(short)b2h,(short)b2l, BF16_ONE, BF16_ONE, 0,0,0 };
        char* tbase = cands + (c >> 5) * 1024 + (c & 31) * 16;
        *(short8*)(tbase)       = kg0;
        *(short8*)(tbase + 512) = kg1;
    }

    // ---- A-frags (row = lane&31, k = (lane>>5)*8 + j), 64 queries/wave ----
    short8 af0, af1;
    const float* qb = Q + ((size_t)batch * NPTS + (size_t)qc * 256) * 3;
    #pragma unroll
    for (int qt = 0; qt < 2; ++qt) {
        const int qi = (wid * 2 + qt) * 32 + lr;
        float x = qb[qi*3+0], y = qb[qi*3+1], z = qb[qi*3+2];
        unsigned short hx = f2bf(x), hy = f2bf(y), hz = f2bf(z);
        unsigned short lx = f2bf(x - bf2f(hx));
        unsigned short ly = f2bf(y - bf2f(hy));
        unsigned short lz = f2bf(z - bf2f(hz));
        float a2 = fmaf(x,x, fmaf(y,y, z*z));
        unsigned short a2h = f2bf(a2);
        unsigned short a2l = f2bf(a2 - bf2f(a2h));
        short8 f;
        if (lh == 0)
            f = (short8){ (short)hx,(short)hy,(short)hz,(short)lx,(short)ly,(short)lz,(short)hx,(short)hy };
        else
            f = (short8){ (short)hz, BF16_ONE, BF16_ONE, (short)a2h,(short)a2l, 0,0,0 };
        if (qt == 0) af0 = f; else af1 = f;
    }
    __syncthreads();

    // ---- main loop: 16 iters x {2 b128 reads, 4 MFMA, 32 umin3} ----
    u32x16 mnU, mnU2;
    f32x16 zero16;
    #pragma unroll
    for (int r = 0; r < 16; ++r) { mnU[r] = FMAX_BITS; mnU2[r] = FMAX_BITS; zero16[r] = 0.f; }

    const char* cp = cands + lh * 512 + lr * 16;
    for (int ct = 0; ct < CTILES; ct += 2) {
        short8 b0 = *(const short8*)(cp);
        short8 b1 = *(const short8*)(cp + 1024);
        cp += 2048;
        {
            f32x16 a00 = __builtin_amdgcn_mfma_f32_32x32x16_bf16(af0, b0, zero16, 0,0,0);
            f32x16 a01 = __builtin_amdgcn_mfma_f32_32x32x16_bf16(af0, b1, zero16, 0,0,0);
            #pragma unroll
            for (int r = 0; r < 16; ++r)
                mnU[r] = umin2(umin2(f2u(a00[r]), f2u(a01[r])), mnU[r]);   // v_min3_u32
        }
        {
            f32x16 a10 = __builtin_amdgcn_mfma_f32_32x32x16_bf16(af1, b0, zero16, 0,0,0);
            f32x16 a11 = __builtin_amdgcn_mfma_f32_32x32x16_bf16(af1, b1, zero16, 0,0,0);
            #pragma unroll
            for (int r = 0; r < 16; ++r)
                mnU2[r] = umin2(umin2(f2u(a10[r]), f2u(a11[r])), mnU2[r]);
        }
    }

    // ---- epilogue: candidate-min within 32-lane group; write per-query mins ----
    // D layout: col = lane&31, row = (r&3) + 8*(r>>2) + 4*lh
    float* pb = pmin + ((size_t)g * CC + cc) * 256;
    #pragma unroll
    for (int r = 0; r < 16; ++r) {
        const int crow = (r & 3) + 8 * (r >> 2) + 4 * lh;
        unsigned v = mnU[r];
        v = umin2(v, (unsigned)__shfl_xor((int)v, 1, 64));
        v = umin2(v, (unsigned)__shfl_xor((int)v, 2, 64));
        v = umin2(v, (unsigned)__shfl_xor((int)v, 4, 64));
        v = umin2(v, (unsigned)__shfl_xor((int)v, 8, 64));
        v = umin2(v, (unsigned)__shfl_xor((int)v, 16, 64));
        if (lr == 0) pb[(wid * 2 + 0) * 32 + crow] = u2f(v);
        unsigned w = mnU2[r];
        w = umin2(w, (unsigned)__shfl_xor((int)w, 1, 64));
        w = umin2(w, (unsigned)__shfl_xor((int)w, 2, 64));
        w = umin2(w, (unsigned)__shfl_xor((int)w, 4, 64));
        w = umin2(w, (unsigned)__shfl_xor((int)w, 8, 64));
        w = umin2(w, (unsigned)__shfl_xor((int)w, 16, 64));
        if (lr == 0) pb[(wid * 2 + 1) * 32 + crow] = u2f(w);
    }
}

// ---- kernel 2: min across CC chunks, sum per group -------------------------
__global__ __launch_bounds__(256) void combine_kernel(
    const float* __restrict__ pmin, float* __restrict__ partial)
{
    const int g   = blockIdx.x;    // 0..511
    const int tid = threadIdx.x;
    const float* p0 = pmin + (size_t)g * CC * 256;
    unsigned a = f2u(p0[tid]), b = f2u(p0[256 + tid]);
    float s = u2f(umin2(a, b));
    #pragma unroll
    for (int o = 32; o > 0; o >>= 1) s += __shfl_down(s, o, 64);
    __shared__ float wsum[4];
    const int lane = tid & 63, wid = tid >> 6;
    if (lane == 0) wsum[wid] = s;
    __syncthreads();
    if (tid == 0) partial[g] = (wsum[0] + wsum[1]) + (wsum[2] + wsum[3]);
}

// ---- kernel 3: 512-sum + cross-entropy + output ----------------------------
__global__ __launch_bounds__(256) void finalize_kernel(
    const float* __restrict__ partial, const float* __restrict__ pred,
    const int* __restrict__ gt, float* __restrict__ out)
{
    __shared__ float s_ce[BATCH];
    __shared__ float wsum[4];
    const int tid = threadIdx.x;

    float v = partial[tid] + partial[tid + 256];
    #pragma unroll
    for (int o = 32; o > 0; o >>= 1) v += __shfl_down(v, o, 64);
    const int lane = tid & 63, wid = tid >> 6;
    if (lane == 0) wsum[wid] = v;

    if (tid < BATCH) {
        const float* row = pred + tid * NUM_CLASSES;
        float mx = row[0];
        #pragma unroll
        for (int c = 1; c < NUM_CLASSES; ++c) mx = fmaxf(mx, row[c]);
        float se = 0.f;
        #pragma unroll
        for (int c = 0; c < NUM_CLASSES; ++c) se += __expf(row[c] - mx);
        const int lbl = gt[tid];
        s_ce[tid] = -(row[lbl] - mx - __logf(se));
    }
    __syncthreads();

    if (tid == 0) {
        float cd = ((wsum[0] + wsum[1]) + (wsum[2] + wsum[3])) / (float)(BATCH * NPTS);
        float ce = 0.f;
        for (int i = 0; i < BATCH; ++i) ce += s_ce[i];
        ce /= (float)BATCH;
        out[0] = 5.f * cd + ce;
        out[1] = cd;
        out[2] = ce;
    }
}

extern "C" void kernel_launch(void* const* d_in, const int* in_sizes, int n_in,
                              void* d_out, int out_size, void* d_ws, size_t ws_size,
                              hipStream_t stream) {
    const float* inst  = (const float*)d_in[0];
    const float* model = (const float*)d_in[1];
    const float* pred  = (const float*)d_in[2];
    const int*   gt    = (const int*)d_in[3];
    float* out = (float*)d_out;
    float* ws  = (float*)d_ws;

    chamfer_pass1<<<GROUPS * CC, THREADS, 0, stream>>>(inst, model, ws);
    combine_kernel<<<GROUPS, 256, 0, stream>>>(ws, ws + PART_OFF);
    finalize_kernel<<<1, 256, 0, stream>>>(ws + PART_OFF, pred, gt, out);
}

// Round 18
// 18.953 us; speedup vs baseline: 1.2880x; 1.2880x over previous
//
#include <hip/hip_runtime.h>

typedef __attribute__((ext_vector_type(8)))  short short8;
typedef __attribute__((ext_vector_type(16))) float f32x16;
typedef __attribute__((ext_vector_type(16))) unsigned u32x16;

#define NPTS 2048
#define BATCH 32
#define NUM_CLASSES 6
#define THREADS 256
// grid = 2 dirs * 32 batches * 8 qchunks = 512 blocks
#define BF16_ONE ((short)0x3F80)
#define FMAX_BITS 0x7F7FFFFFu

__device__ __forceinline__ unsigned short f2bf(float x) {
    union { float f; unsigned u; } v; v.f = x;
    unsigned r = v.u + 0x7FFF + ((v.u >> 16) & 1);   // RNE to bf16
    return (unsigned short)(r >> 16);
}
__device__ __forceinline__ float bf2f(unsigned short h) {
    union { unsigned u; float f; } v; v.u = ((unsigned)h) << 16; return v.f;
}
__device__ __forceinline__ unsigned f2u(float x) {
    union { float f; unsigned u; } v; v.f = x; return v.u;
}
__device__ __forceinline__ float u2f(unsigned x) {
    union { unsigned u; float f; } v; v.u = x; return v.f;
}
// Distances strictly positive -> uint compare == float compare; umin chains
// match v_min3_u32, no canonicalize, no inline asm (R14/R15 lessons).
__device__ __forceinline__ unsigned umin2(unsigned a, unsigned b) {
    return a < b ? a : b;
}

// K-slot plan (K=16), D = a2 + b2 - 2 a.b (absmax-0 verified R3-R16):
//  k0-2: A=ah B=-2bh | k3-5: A=al B=-2bh | k6-8: A=ah B=-2bl
//  k9: A=1 B=b2h | k10: A=1 B=b2l | k11: A=a2h B=1 | k12: A=a2l B=1 | k13-15: 0
// LDS: per 32-cand tile, 1024 B = [32 x kg0][32 x kg1]; one ds_read_b128 per
// wave delivers a full tile, conflict-free (R13: SQ_LDS_BANK_CONFLICT=0).
// __launch_bounds__(256,2): 256-VGPR budget, the R15-proven register mode.
//
// 2-deep software pipeline over 32 stages x 2 tiles (R17 bug: ran 16 stages =
// half the candidates; stage s = tiles 2s,2s+1, s=0..31, 64 tiles total).
// Each steady iteration issues {reads s+1 | MFMA s | fold s-1} to keep the
// DS, matrix and VALU pipes concurrently busy within one wave (R15 measured
// exact serial-sum 8.3 us = 3.4 mfma + 2.6 ds + 1.7 valu, zero overlap).
__global__ __launch_bounds__(THREADS, 2) void chamfer_mfma32(
    const float* __restrict__ inst, const float* __restrict__ model,
    float* __restrict__ partial)
{
    __shared__ char  cands[NPTS * 32];   // 64 KB
    __shared__ float wsum[4];

    const int blk   = blockIdx.x;
    const int dir   = blk >> 8;
    const int batch = (blk >> 3) & 31;
    const int qc    = blk & 7;
    const int tid   = threadIdx.x;
    const int lane  = tid & 63, wid = tid >> 6;
    const int lh    = lane >> 5, lr = lane & 31;

    const float* __restrict__ Q = dir ? model : inst;
    const float* __restrict__ C = dir ? inst  : model;

    // ---- stage candidates into tiled B-frag layout ----
    const float* cb = C + (size_t)batch * NPTS * 3;
    for (int c = tid; c < NPTS; c += THREADS) {
        float bx = cb[c*3+0], by = cb[c*3+1], bz = cb[c*3+2];
        float m2x = -2.f*bx, m2y = -2.f*by, m2z = -2.f*bz;
        unsigned short hx = f2bf(m2x), hy = f2bf(m2y), hz = f2bf(m2z);
        unsigned short lx = f2bf(m2x - bf2f(hx));
        unsigned short ly = f2bf(m2y - bf2f(hy));
        unsigned short lz = f2bf(m2z - bf2f(hz));
        float b2 = fmaf(bx,bx, fmaf(by,by, bz*bz));
        unsigned short b2h = f2bf(b2);
        unsigned short b2l = f2bf(b2 - bf2f(b2h));
        short8 kg0 = { (short)hx,(short)hy,(short)hz,(short)hx,(short)hy,(short)hz,(short)lx,(short)ly };
        short8 kg1 = { (short)lz,(short)b2h,(short)b2l, BF16_ONE, BF16_ONE, 0,0,0 };
        char* tbase = cands + (c >> 5) * 1024 + (c & 31) * 16;
        *(short8*)(tbase)       = kg0;
        *(short8*)(tbase + 512) = kg1;
    }

    // ---- A-frags from global (row = lane&31, k = (lane>>5)*8 + j) ----
    short8 af0, af1;
    const float* qb = Q + ((size_t)batch * NPTS + (size_t)qc * 256) * 3;
    #pragma unroll
    for (int qt = 0; qt < 2; ++qt) {
        const int qi = (wid * 2 + qt) * 32 + lr;
        float x = qb[qi*3+0], y = qb[qi*3+1], z = qb[qi*3+2];
        unsigned short hx = f2bf(x), hy = f2bf(y), hz = f2bf(z);
        unsigned short lx = f2bf(x - bf2f(hx));
        unsigned short ly = f2bf(y - bf2f(hy));
        unsigned short lz = f2bf(z - bf2f(hz));
        float a2 = fmaf(x,x, fmaf(y,y, z*z));
        unsigned short a2h = f2bf(a2);
        unsigned short a2l = f2bf(a2 - bf2f(a2h));
        short8 f;
        if (lh == 0)
            f = (short8){ (short)hx,(short)hy,(short)hz,(short)lx,(short)ly,(short)lz,(short)hx,(short)hy };
        else
            f = (short8){ (short)hz, BF16_ONE, BF16_ONE, (short)a2h,(short)a2l, 0,0,0 };
        if (qt == 0) af0 = f; else af1 = f;
    }
    __syncthreads();

    // ---- software-pipelined main loop: 32 stages of 2 tiles ----
    u32x16 mnU, mnU2;
    f32x16 zero16;
    #pragma unroll
    for (int r = 0; r < 16; ++r) { mnU[r] = FMAX_BITS; mnU2[r] = FMAX_BITS; zero16[r] = 0.f; }

    const char* cp = cands + lh * 512 + lr * 16;
    // prologue: stage 0 tiles + stage 1 prefetch
    short8 c0 = *(const short8*)(cp);
    short8 c1 = *(const short8*)(cp + 1024);
    short8 n0 = *(const short8*)(cp + 2048);
    short8 n1 = *(const short8*)(cp + 3072);
    cp += 4096;
    f32x16 p00 = __builtin_amdgcn_mfma_f32_32x32x16_bf16(af0, c0, zero16, 0,0,0);
    f32x16 p01 = __builtin_amdgcn_mfma_f32_32x32x16_bf16(af0, c1, zero16, 0,0,0);
    f32x16 p10 = __builtin_amdgcn_mfma_f32_32x32x16_bf16(af1, c0, zero16, 0,0,0);
    f32x16 p11 = __builtin_amdgcn_mfma_f32_32x32x16_bf16(af1, c1, zero16, 0,0,0);

    #pragma unroll 2
    for (int s = 1; s < 31; ++s) {        // stages 1..30 (tiles 2..61)
        c0 = n0; c1 = n1;
        n0 = *(const short8*)(cp);        // prefetch stage s+1
        n1 = *(const short8*)(cp + 1024);
        cp += 2048;
        f32x16 q00 = __builtin_amdgcn_mfma_f32_32x32x16_bf16(af0, c0, zero16, 0,0,0);
        f32x16 q01 = __builtin_amdgcn_mfma_f32_32x32x16_bf16(af0, c1, zero16, 0,0,0);
        f32x16 q10 = __builtin_amdgcn_mfma_f32_32x32x16_bf16(af1, c0, zero16, 0,0,0);
        f32x16 q11 = __builtin_amdgcn_mfma_f32_32x32x16_bf16(af1, c1, zero16, 0,0,0);
        #pragma unroll
        for (int r = 0; r < 16; ++r)      // fold stage s-1 (completed)
            mnU[r]  = umin2(umin2(f2u(p00[r]), f2u(p01[r])), mnU[r]);
        #pragma unroll
        for (int r = 0; r < 16; ++r)
            mnU2[r] = umin2(umin2(f2u(p10[r]), f2u(p11[r])), mnU2[r]);
        p00 = q00; p01 = q01; p10 = q10; p11 = q11;
    }
    {   // stage 31 (tiles 62,63, prefetched in n0/n1) + drain folds
        f32x16 q00 = __builtin_amdgcn_mfma_f32_32x32x16_bf16(af0, n0, zero16, 0,0,0);
        f32x16 q01 = __builtin_amdgcn_mfma_f32_32x32x16_bf16(af0, n1, zero16, 0,0,0);
        f32x16 q10 = __builtin_amdgcn_mfma_f32_32x32x16_bf16(af1, n0, zero16, 0,0,0);
        f32x16 q11 = __builtin_amdgcn_mfma_f32_32x32x16_bf16(af1, n1, zero16, 0,0,0);
        #pragma unroll
        for (int r = 0; r < 16; ++r) {
            mnU[r]  = umin2(umin2(f2u(p00[r]), f2u(p01[r])), mnU[r]);
            mnU2[r] = umin2(umin2(f2u(p10[r]), f2u(p11[r])), mnU2[r]);
        }
        #pragma unroll
        for (int r = 0; r < 16; ++r) {
            mnU[r]  = umin2(umin2(f2u(q00[r]), f2u(q01[r])), mnU[r]);
            mnU2[r] = umin2(umin2(f2u(q10[r]), f2u(q11[r])), mnU2[r]);
        }
    }

    // ---- epilogue: min across 32 candidate-cols (lanes within 32-group), sum ----
    float s = 0.f;
    #pragma unroll
    for (int r = 0; r < 16; ++r) {
        unsigned v = mnU[r];
        v = umin2(v, (unsigned)__shfl_xor((int)v, 1, 64));
        v = umin2(v, (unsigned)__shfl_xor((int)v, 2, 64));
        v = umin2(v, (unsigned)__shfl_xor((int)v, 4, 64));
        v = umin2(v, (unsigned)__shfl_xor((int)v, 8, 64));
        v = umin2(v, (unsigned)__shfl_xor((int)v, 16, 64));
        s += u2f(v);
        unsigned w = mnU2[r];
        w = umin2(w, (unsigned)__shfl_xor((int)w, 1, 64));
        w = umin2(w, (unsigned)__shfl_xor((int)w, 2, 64));
        w = umin2(w, (unsigned)__shfl_xor((int)w, 4, 64));
        w = umin2(w, (unsigned)__shfl_xor((int)w, 8, 64));
        w = umin2(w, (unsigned)__shfl_xor((int)w, 16, 64));
        s += u2f(w);
    }
    s += __shfl_xor(s, 32, 64);      // combine lh=0 / lh=1 query halves
    if (lane == 0) wsum[wid] = s;
    __syncthreads();
    if (tid == 0) partial[blk] = (wsum[0] + wsum[1]) + (wsum[2] + wsum[3]);
}

__global__ __launch_bounds__(256) void finalize_kernel(
    const float* __restrict__ partial, const float* __restrict__ pred,
    const int* __restrict__ gt, float* __restrict__ out)
{
    __shared__ float s_ce[BATCH];
    __shared__ float wsum[4];
    const int tid = threadIdx.x;

    float v = partial[tid] + partial[tid + 256];
    #pragma unroll
    for (int o = 32; o > 0; o >>= 1) v += __shfl_down(v, o, 64);
    const int lane = tid & 63, wid = tid >> 6;
    if (lane == 0) wsum[wid] = v;

    if (tid < BATCH) {
        const float* row = pred + tid * NUM_CLASSES;
        float mx = row[0];
        #pragma unroll
        for (int c = 1; c < NUM_CLASSES; ++c) mx = fmaxf(mx, row[c]);
        float se = 0.f;
        #pragma unroll
        for (int c = 0; c < NUM_CLASSES; ++c) se += __expf(row[c] - mx);
        const int lbl = gt[tid];
        s_ce[tid] = -(row[lbl] - mx - __logf(se));
    }
    __syncthreads();

    if (tid == 0) {
        float cd_sum = (wsum[0] + wsum[1]) + (wsum[2] + wsum[3]);
        float cd = cd_sum / (float)(BATCH * NPTS);
        float ce = 0.f;
        for (int i = 0; i < BATCH; ++i) ce += s_ce[i];
        ce /= (float)BATCH;
        out[0] = 5.f * cd + ce;
        out[1] = cd;
        out[2] = ce;
    }
}

extern "C" void kernel_launch(void* const* d_in, const int* in_sizes, int n_in,
                              void* d_out, int out_size, void* d_ws, size_t ws_size,
                              hipStream_t stream) {
    const float* inst  = (const float*)d_in[0];
    const float* model = (const float*)d_in[1];
    const float* pred  = (const float*)d_in[2];
    const int*   gt    = (const int*)d_in[3];
    float* out     = (float*)d_out;
    float* partial = (float*)d_ws;   // 512 floats

    chamfer_mfma32<<<512, THREADS, 0, stream>>>(inst, model, partial);
    finalize_kernel<<<1, 256, 0, stream>>>(partial, pred, gt, out);
}

// Round 19
// 17.859 us; speedup vs baseline: 1.3669x; 1.0613x over previous
//
#include <hip/hip_runtime.h>

typedef __attribute__((ext_vector_type(8)))  short short8;
typedef __attribute__((ext_vector_type(16))) float f32x16;
typedef __attribute__((ext_vector_type(16))) unsigned u32x16;

#define NPTS 2048
#define BATCH 32
#define NUM_CLASSES 6
#define THREADS 256
// grid = 2 dirs * 32 batches * 8 qchunks = 512 blocks
#define BF16_ONE ((short)0x3F80)
#define FMAX_BITS 0x7F7FFFFFu

__device__ __forceinline__ unsigned short f2bf(float x) {
    union { float f; unsigned u; } v; v.f = x;
    unsigned r = v.u + 0x7FFF + ((v.u >> 16) & 1);   // RNE to bf16
    return (unsigned short)(r >> 16);
}
__device__ __forceinline__ float bf2f(unsigned short h) {
    union { unsigned u; float f; } v; v.u = ((unsigned)h) << 16; return v.f;
}
__device__ __forceinline__ unsigned f2u(float x) {
    union { float f; unsigned u; } v; v.f = x; return v.u;
}
__device__ __forceinline__ float u2f(unsigned x) {
    union { unsigned u; float f; } v; v.u = x; return v.f;
}
// Distances strictly positive -> uint compare == float compare; umin chains
// match v_min3_u32, no canonicalize, no inline asm (R14/R15 lessons).
__device__ __forceinline__ unsigned umin2(unsigned a, unsigned b) {
    return a < b ? a : b;
}
// DS-pipe-free 16-lane row min via DPP row_ror (VALU only). R18's epilogue
// was 160 shfl_xor (DS pipe) per wave ~= 3 us/CU; this cuts DS ops to 32.
template<int CTRL>
__device__ __forceinline__ unsigned dpp_ror_umin(unsigned v) {
    unsigned r = (unsigned)__builtin_amdgcn_update_dpp((int)v, (int)v, CTRL, 0xF, 0xF, false);
    return umin2(v, r);
}
__device__ __forceinline__ unsigned swz16_umin(unsigned v) {
    unsigned r = (unsigned)__builtin_amdgcn_ds_swizzle((int)v, 0x401F);  // lane^16
    return umin2(v, r);
}

// K-slot plan (K=16), D = a2 + b2 - 2 a.b (absmax-0 verified R3-R18):
//  k0-2: A=ah B=-2bh | k3-5: A=al B=-2bh | k6-8: A=ah B=-2bl
//  k9: A=1 B=b2h | k10: A=1 B=b2l | k11: A=a2h B=1 | k12: A=a2l B=1 | k13-15: 0
// LDS: per 32-cand tile, 1024 B = [32 x kg0][32 x kg1]; one ds_read_b128 per
// wave delivers a full tile, conflict-free (R13: SQ_LDS_BANK_CONFLICT=0).
// __launch_bounds__(256,2): 256-VGPR budget, the R15-proven register mode.
// 2-deep software pipeline over 32 stages x 2 tiles (R18-verified).
__global__ __launch_bounds__(THREADS, 2) void chamfer_mfma32(
    const float* __restrict__ inst, const float* __restrict__ model,
    float* __restrict__ partial)
{
    __shared__ char  cands[NPTS * 32];   // 64 KB
    __shared__ float wsum[4];

    const int blk   = blockIdx.x;
    const int dir   = blk >> 8;
    const int batch = (blk >> 3) & 31;
    const int qc    = blk & 7;
    const int tid   = threadIdx.x;
    const int lane  = tid & 63, wid = tid >> 6;
    const int lh    = lane >> 5, lr = lane & 31;

    const float* __restrict__ Q = dir ? model : inst;
    const float* __restrict__ C = dir ? inst  : model;

    // ---- stage candidates into tiled B-frag layout ----
    const float* cb = C + (size_t)batch * NPTS * 3;
    for (int c = tid; c < NPTS; c += THREADS) {
        float bx = cb[c*3+0], by = cb[c*3+1], bz = cb[c*3+2];
        float m2x = -2.f*bx, m2y = -2.f*by, m2z = -2.f*bz;
        unsigned short hx = f2bf(m2x), hy = f2bf(m2y), hz = f2bf(m2z);
        unsigned short lx = f2bf(m2x - bf2f(hx));
        unsigned short ly = f2bf(m2y - bf2f(hy));
        unsigned short lz = f2bf(m2z - bf2f(hz));
        float b2 = fmaf(bx,bx, fmaf(by,by, bz*bz));
        unsigned short b2h = f2bf(b2);
        unsigned short b2l = f2bf(b2 - bf2f(b2h));
        short8 kg0 = { (short)hx,(short)hy,(short)hz,(short)hx,(short)hy,(short)hz,(short)lx,(short)ly };
        short8 kg1 = { (short)lz,(short)b2h,(short)b2l, BF16_ONE, BF16_ONE, 0,0,0 };
        char* tbase = cands + (c >> 5) * 1024 + (c & 31) * 16;
        *(short8*)(tbase)       = kg0;
        *(short8*)(tbase + 512) = kg1;
    }

    // ---- A-frags from global (row = lane&31, k = (lane>>5)*8 + j) ----
    short8 af0, af1;
    const float* qb = Q + ((size_t)batch * NPTS + (size_t)qc * 256) * 3;
    #pragma unroll
    for (int qt = 0; qt < 2; ++qt) {
        const int qi = (wid * 2 + qt) * 32 + lr;
        float x = qb[qi*3+0], y = qb[qi*3+1], z = qb[qi*3+2];
        unsigned short hx = f2bf(x), hy = f2bf(y), hz = f2bf(z);
        unsigned short lx = f2bf(x - bf2f(hx));
        unsigned short ly = f2bf(y - bf2f(hy));
        unsigned short lz = f2bf(z - bf2f(hz));
        float a2 = fmaf(x,x, fmaf(y,y, z*z));
        unsigned short a2h = f2bf(a2);
        unsigned short a2l = f2bf(a2 - bf2f(a2h));
        short8 f;
        if (lh == 0)
            f = (short8){ (short)hx,(short)hy,(short)hz,(short)lx,(short)ly,(short)lz,(short)hx,(short)hy };
        else
            f = (short8){ (short)hz, BF16_ONE, BF16_ONE, (short)a2h,(short)a2l, 0,0,0 };
        if (qt == 0) af0 = f; else af1 = f;
    }
    __syncthreads();

    // ---- software-pipelined main loop: 32 stages of 2 tiles ----
    u32x16 mnU, mnU2;
    f32x16 zero16;
    #pragma unroll
    for (int r = 0; r < 16; ++r) { mnU[r] = FMAX_BITS; mnU2[r] = FMAX_BITS; zero16[r] = 0.f; }

    const char* cp = cands + lh * 512 + lr * 16;
    // prologue: stage 0 tiles + stage 1 prefetch
    short8 c0 = *(const short8*)(cp);
    short8 c1 = *(const short8*)(cp + 1024);
    short8 n0 = *(const short8*)(cp + 2048);
    short8 n1 = *(const short8*)(cp + 3072);
    cp += 4096;
    f32x16 p00 = __builtin_amdgcn_mfma_f32_32x32x16_bf16(af0, c0, zero16, 0,0,0);
    f32x16 p01 = __builtin_amdgcn_mfma_f32_32x32x16_bf16(af0, c1, zero16, 0,0,0);
    f32x16 p10 = __builtin_amdgcn_mfma_f32_32x32x16_bf16(af1, c0, zero16, 0,0,0);
    f32x16 p11 = __builtin_amdgcn_mfma_f32_32x32x16_bf16(af1, c1, zero16, 0,0,0);

    #pragma unroll 2
    for (int s = 1; s < 31; ++s) {        // stages 1..30 (tiles 2..61)
        c0 = n0; c1 = n1;
        n0 = *(const short8*)(cp);        // prefetch stage s+1
        n1 = *(const short8*)(cp + 1024);
        cp += 2048;
        f32x16 q00 = __builtin_amdgcn_mfma_f32_32x32x16_bf16(af0, c0, zero16, 0,0,0);
        f32x16 q01 = __builtin_amdgcn_mfma_f32_32x32x16_bf16(af0, c1, zero16, 0,0,0);
        f32x16 q10 = __builtin_amdgcn_mfma_f32_32x32x16_bf16(af1, c0, zero16, 0,0,0);
        f32x16 q11 = __builtin_amdgcn_mfma_f32_32x32x16_bf16(af1, c1, zero16, 0,0,0);
        #pragma unroll
        for (int r = 0; r < 16; ++r)      // fold stage s-1 (completed)
            mnU[r]  = umin2(umin2(f2u(p00[r]), f2u(p01[r])), mnU[r]);
        #pragma unroll
        for (int r = 0; r < 16; ++r)
            mnU2[r] = umin2(umin2(f2u(p10[r]), f2u(p11[r])), mnU2[r]);
        p00 = q00; p01 = q01; p10 = q10; p11 = q11;
    }
    {   // stage 31 (tiles 62,63, prefetched in n0/n1) + drain folds
        f32x16 q00 = __builtin_amdgcn_mfma_f32_32x32x16_bf16(af0, n0, zero16, 0,0,0);
        f32x16 q01 = __builtin_amdgcn_mfma_f32_32x32x16_bf16(af0, n1, zero16, 0,0,0);
        f32x16 q10 = __builtin_amdgcn_mfma_f32_32x32x16_bf16(af1, n0, zero16, 0,0,0);
        f32x16 q11 = __builtin_amdgcn_mfma_f32_32x32x16_bf16(af1, n1, zero16, 0,0,0);
        #pragma unroll
        for (int r = 0; r < 16; ++r) {
            mnU[r]  = umin2(umin2(f2u(p00[r]), f2u(p01[r])), mnU[r]);
            mnU2[r] = umin2(umin2(f2u(p10[r]), f2u(p11[r])), mnU2[r]);
        }
        #pragma unroll
        for (int r = 0; r < 16; ++r) {
            mnU[r]  = umin2(umin2(f2u(q00[r]), f2u(q01[r])), mnU[r]);
            mnU2[r] = umin2(umin2(f2u(q10[r]), f2u(q11[r])), mnU2[r]);
        }
    }

    // ---- epilogue: 32-lane candidate-min via DPP row_ror (VALU) + 1 swizzle ----
    // Verified pattern (R6/R10 passed absmax-0): ror 1,2,4,8 -> 16-lane row
    // min in every lane; ds_swizzle xor16 -> full 32-lane group min.
    float s = 0.f;
    #pragma unroll
    for (int r = 0; r < 16; ++r) {
        unsigned v = mnU[r];
        v = dpp_ror_umin<0x121>(v);   // row_ror:1
        v = dpp_ror_umin<0x122>(v);   // row_ror:2
        v = dpp_ror_umin<0x124>(v);   // row_ror:4
        v = dpp_ror_umin<0x128>(v);   // row_ror:8
        v = swz16_umin(v);
        s += u2f(v);
        unsigned w = mnU2[r];
        w = dpp_ror_umin<0x121>(w);
        w = dpp_ror_umin<0x122>(w);
        w = dpp_ror_umin<0x124>(w);
        w = dpp_ror_umin<0x128>(w);
        w = swz16_umin(w);
        s += u2f(w);
    }
    s += __shfl_xor(s, 32, 64);      // combine lh=0 / lh=1 query halves
    if (lane == 0) wsum[wid] = s;
    __syncthreads();
    if (tid == 0) partial[blk] = (wsum[0] + wsum[1]) + (wsum[2] + wsum[3]);
}

__global__ __launch_bounds__(256) void finalize_kernel(
    const float* __restrict__ partial, const float* __restrict__ pred,
    const int* __restrict__ gt, float* __restrict__ out)
{
    __shared__ float s_ce[BATCH];
    __shared__ float wsum[4];
    const int tid = threadIdx.x;

    float v = partial[tid] + partial[tid + 256];
    #pragma unroll
    for (int o = 32; o > 0; o >>= 1) v += __shfl_down(v, o, 64);
    const int lane = tid & 63, wid = tid >> 6;
    if (lane == 0) wsum[wid] = v;

    if (tid < BATCH) {
        const float* row = pred + tid * NUM_CLASSES;
        float mx = row[0];
        #pragma unroll
        for (int c = 1; c < NUM_CLASSES; ++c) mx = fmaxf(mx, row[c]);
        float se = 0.f;
        #pragma unroll
        for (int c = 0; c < NUM_CLASSES; ++c) se += __expf(row[c] - mx);
        const int lbl = gt[tid];
        s_ce[tid] = -(row[lbl] - mx - __logf(se));
    }
    __syncthreads();

    if (tid == 0) {
        float cd_sum = (wsum[0] + wsum[1]) + (wsum[2] + wsum[3]);
        float cd = cd_sum / (float)(BATCH * NPTS);
        float ce = 0.f;
        for (int i = 0; i < BATCH; ++i) ce += s_ce[i];
        ce /= (float)BATCH;
        out[0] = 5.f * cd + ce;
        out[1] = cd;
        out[2] = ce;
    }
}

extern "C" void kernel_launch(void* const* d_in, const int* in_sizes, int n_in,
                              void* d_out, int out_size, void* d_ws, size_t ws_size,
                              hipStream_t stream) {
    const float* inst  = (const float*)d_in[0];
    const float* model = (const float*)d_in[1];
    const float* pred  = (const float*)d_in[2];
    const int*   gt    = (const int*)d_in[3];
    float* out     = (float*)d_out;
    float* partial = (float*)d_ws;   // 512 floats

    chamfer_mfma32<<<512, THREADS, 0, stream>>>(inst, model, partial);
    finalize_kernel<<<1, 256, 0, stream>>>(partial, pred, gt, out);
}